// Round 17
// baseline (54.374 us; speedup 1.0000x reference)
//
#include <hip/hip_runtime.h>
#include <cstddef>

#define NB 8
#define TQ 2048
#define TV 2048
#define DD 128
#define KVT 32
#define NWV 4           // waves per block; chunk = 512 KV rows/wave (PROVEN shape)
#define CHW (TV / NWV)  // 512
#define NT  (CHW / KVT) // 16 tiles per wave
#define LOG2E 1.4426950408889634f

typedef _Float16 f16x8 __attribute__((ext_vector_type(8)));
typedef _Float16 f16x4 __attribute__((ext_vector_type(4)));
typedef float f32x4 __attribute__((ext_vector_type(4)));

__device__ __forceinline__ float fast_exp2(float x) {
  return __builtin_amdgcn_exp2f(x);      // v_exp_f32 (computes 2^x)
}

// ------- prepass (r15-verified) ---------------------------------------------
// kh2: f16(k) tiled [B][64 kt][4 kc][32 Row][32 dk], rows PERMUTED so that the
//      swapped-QK^T MFMA lands scores at kv = 8*lg + 4*kvf + r (in-register P).
// vt2: f16(v)^T tiled [B][64 kt][128 d][32 kv], masked kv columns ZEROED.
// indb: f16 indicator [B][TV]  (1 = valid kv, 0 = masked)
__global__ __launch_bounds__(256) void prepass_kernel(
    const float* __restrict__ k, const float* __restrict__ v,
    const int* __restrict__ mask_v,
    _Float16* __restrict__ kh2, _Float16* __restrict__ vt2,
    _Float16* __restrict__ indb)
{
  __shared__ _Float16 tlds[32 * 34];
  const int tid = threadIdx.x;
  const int bid = blockIdx.x;
  if (bid < 512) {                        // K tiles: one 32x128 tile per block
    int b = bid >> 6, kt = bid & 63;
    int row = tid >> 3, d0 = (tid & 7) * 4;          // row = original kv 0..31
    int R = 16 * ((row >> 2) & 1) + 4 * (row >> 3) + (row & 3);  // storage row
    const float* src = k + ((size_t)(b * TV + kt * 32 + row)) * DD;
    _Float16* dst = kh2 + ((size_t)(b * 64 + kt)) * 4096;
#pragma unroll
    for (int it = 0; it < 4; ++it) {      // kc = it
      float4 x = *(const float4*)(src + it * 32 + d0);
      f16x4 h; h[0] = (_Float16)x.x; h[1] = (_Float16)x.y;
      h[2] = (_Float16)x.z; h[3] = (_Float16)x.w;
      *(f16x4*)(dst + it * 1024 + R * 32 + d0) = h;
    }
  } else if (bid < 512 + 2048) {          // V transpose tiles 32x32 (masked->0)
    int tb = bid - 512;                   // 8 b * 64 kt * 4 dt
    int b = tb >> 8, rem = tb & 255;
    int kt = rem >> 2, dt = rem & 3;
    int r = tid >> 3, c0 = (tid & 7) * 4;
    float mfac = (mask_v[(size_t)b * TV + kt * 32 + r] != 0) ? 1.f : 0.f;
    float4 x = *(const float4*)&v[((size_t)b * TV + kt * 32 + r) * DD + dt * 32 + c0];
    tlds[(c0 + 0) * 34 + r] = (_Float16)(mfac * x.x);
    tlds[(c0 + 1) * 34 + r] = (_Float16)(mfac * x.y);
    tlds[(c0 + 2) * 34 + r] = (_Float16)(mfac * x.z);
    tlds[(c0 + 3) * 34 + r] = (_Float16)(mfac * x.w);
    __syncthreads();
    int dl = tid >> 3, k0 = (tid & 7) * 4;
    f16x4 h;
#pragma unroll
    for (int i = 0; i < 4; ++i) h[i] = tlds[dl * 34 + k0 + i];
    size_t eidx = (((size_t)b * 64 + kt) * 128 + (dt * 32 + dl)) * 32 + k0;
    *(f16x4*)&vt2[eidx] = h;
  } else {                                // indicator build: 16 blocks
    int bid2 = bid - 512 - 2048;
    size_t base = (size_t)bid2 * 1024 + tid * 4;
#pragma unroll
    for (int i = 0; i < 4; ++i)
      indb[base + i] = (mask_v[base + i] != 0) ? (_Float16)1.f : (_Float16)0.f;
  }
}

// ------- main: grid 512 (b=blk&7), 4 waves x 32 Q rows x 512-KV chunk ----------
// All-resident pipeline: K, V, AND ind prefetched one tile ahead (parity bufs).
// Zero same-tile load-use; every vmcnt wait targets loads >=1 tile old.
__global__ __launch_bounds__(256, 2) void attn_main(
    const float* __restrict__ q, const float* __restrict__ scale_p,
    const _Float16* __restrict__ kh2, const _Float16* __restrict__ vt2,
    const _Float16* __restrict__ indb,
    const int* __restrict__ mask_q, float* __restrict__ out)
{
  __shared__ __align__(16) float osh[32 * 132];
  __shared__ float msh[NWV][32], lsh[NWV][32];

  const int tid = threadIdx.x;
  const int w = tid >> 6;
  const int lane = tid & 63;
  const int l15 = lane & 15, lg = lane >> 4;

  const int b = blockIdx.x & 7;            // batch -> XCD affinity (proven mapping)
  const int qg = blockIdx.x >> 3;          // 0..63
  const int qbase = qg * 32;

  const _Float16* ktiles = kh2 + (size_t)b * 64 * 4096;
  const _Float16* vtiles = vt2 + (size_t)b * 64 * 4096;
  const _Float16* indbt = indb + (size_t)b * TV;

  // ---- fused Q cast with scale*log2e (B-operand: col = l15 = q row) ----
  const float sc2 = scale_p[0] * LOG2E;
  f16x8 qf[2][4];
#pragma unroll
  for (int rb = 0; rb < 2; ++rb)
#pragma unroll
    for (int kc = 0; kc < 4; ++kc) {
      const float* qp = q + ((size_t)b * TQ + qbase + rb * 16 + l15) * DD + kc * 32 + lg * 8;
      float4 xa = *(const float4*)qp;
      float4 xb = *(const float4*)(qp + 4);
      f16x8 h;
      h[0] = (_Float16)(sc2 * xa.x); h[1] = (_Float16)(sc2 * xa.y);
      h[2] = (_Float16)(sc2 * xa.z); h[3] = (_Float16)(sc2 * xa.w);
      h[4] = (_Float16)(sc2 * xb.x); h[5] = (_Float16)(sc2 * xb.y);
      h[6] = (_Float16)(sc2 * xb.z); h[7] = (_Float16)(sc2 * xb.w);
      qf[rb][kc] = h;
    }

  f32x4 acc[2][8];
  f32x4 accl[2];
#pragma unroll
  for (int rb = 0; rb < 2; ++rb) {
    accl[rb] = (f32x4){0.f, 0.f, 0.f, 0.f};
#pragma unroll
    for (int ct = 0; ct < 8; ++ct) acc[rb][ct] = (f32x4){0.f, 0.f, 0.f, 0.f};
  }
  float m[2];                               // per-lane running max, q = l15
  m[0] = -3.0e38f; m[1] = -3.0e38f;

  const int tbase = w * NT;

  // ---- parity prefetch buffers: K, V, ind all one tile ahead ----
  f16x8 kbuf[2][8];
  f16x8 vbuf[2][8];
  f16x8 indbuf[2];

  // prologue: V(0), K(0), ind(0)
  {
    const _Float16* vt0 = vtiles + (size_t)tbase * 4096;
#pragma unroll
    for (int ct = 0; ct < 8; ++ct)
      vbuf[0][ct] = *(const f16x8*)(vt0 + (ct * 16 + l15) * 32 + lg * 8);
    const _Float16* kt0 = ktiles + (size_t)tbase * 4096;
#pragma unroll
    for (int kc = 0; kc < 4; ++kc) {
      kbuf[0][2 * kc]     = *(const f16x8*)(kt0 + kc * 1024 + l15 * 32 + lg * 8);
      kbuf[0][2 * kc + 1] = *(const f16x8*)(kt0 + kc * 1024 + (16 + l15) * 32 + lg * 8);
    }
    indbuf[0] = *(const f16x8*)(indbt + tbase * 32 + lg * 8);
  }

#pragma unroll
  for (int t = 0; t < NT; ++t) {
    const int p = t & 1;
    const int tile = tbase + t;

    // ---- QK^T swapped on resident kbuf[p] (issued a full tile ago) ----
    f32x4 s[2][2];
    s[0][0] = (f32x4){0,0,0,0}; s[0][1] = (f32x4){0,0,0,0};
    s[1][0] = (f32x4){0,0,0,0}; s[1][1] = (f32x4){0,0,0,0};
    __builtin_amdgcn_s_setprio(1);
#pragma unroll
    for (int kc = 0; kc < 4; ++kc) {
      s[0][0] = __builtin_amdgcn_mfma_f32_16x16x32_f16(kbuf[p][2*kc],   qf[0][kc], s[0][0], 0, 0, 0);
      s[0][1] = __builtin_amdgcn_mfma_f32_16x16x32_f16(kbuf[p][2*kc],   qf[1][kc], s[0][1], 0, 0, 0);
      s[1][0] = __builtin_amdgcn_mfma_f32_16x16x32_f16(kbuf[p][2*kc+1], qf[0][kc], s[1][0], 0, 0, 0);
      s[1][1] = __builtin_amdgcn_mfma_f32_16x16x32_f16(kbuf[p][2*kc+1], qf[1][kc], s[1][1], 0, 0, 0);
    }
    __builtin_amdgcn_s_setprio(0);

    // ---- issue V(t+1), K(t+1), ind(t+1) into the other parity buffer ----
    if (t + 1 < NT) {
      const _Float16* vtn = vtiles + (size_t)(tile + 1) * 4096;
#pragma unroll
      for (int ct = 0; ct < 8; ++ct)
        vbuf[p ^ 1][ct] = *(const f16x8*)(vtn + (ct * 16 + l15) * 32 + lg * 8);
      const _Float16* ktn = ktiles + (size_t)(tile + 1) * 4096;
#pragma unroll
      for (int kc = 0; kc < 4; ++kc) {
        kbuf[p ^ 1][2 * kc]     = *(const f16x8*)(ktn + kc * 1024 + l15 * 32 + lg * 8);
        kbuf[p ^ 1][2 * kc + 1] = *(const f16x8*)(ktn + kc * 1024 + (16 + l15) * 32 + lg * 8);
      }
      indbuf[p ^ 1] = *(const f16x8*)(indbt + (tile + 1) * 32 + lg * 8);
    }

    const f16x8 indf = indbuf[p];           // resident since last tile

    // ---- in-register softmax; NO cross-lane ops on the fast path ----
    // score slot (kvf, r) = kv 8*lg + 4*kvf + r; bias index j = 4*kvf + r
    f16x8 pa[2];
#pragma unroll
    for (int rb = 0; rb < 2; ++rb) {
#pragma unroll
      for (int r = 0; r < 4; ++r) {
        s[0][rb][r] += ((float)indf[r]     - 1.f) * 60000.f;
        s[1][rb][r] += ((float)indf[4 + r] - 1.f) * 60000.f;
      }
      // local (per-lane) max of this lane's 8 scores
      float lm = fmaxf(fmaxf(fmaxf(s[0][rb][0], s[0][rb][1]), fmaxf(s[0][rb][2], s[0][rb][3])),
                       fmaxf(fmaxf(s[1][rb][0], s[1][rb][1]), fmaxf(s[1][rb][2], s[1][rb][3])));
      if (__any(lm > m[rb] + 11.5f)) {      // rare: full rowmax + rescale
        float pm = lm;
        pm = fmaxf(pm, __shfl_xor(pm, 16, 64));
        pm = fmaxf(pm, __shfl_xor(pm, 32, 64));
        float mn = fmaxf(m[rb], pm);
        float alpha = fast_exp2(m[rb] - mn);         // per-lane, q = l15
        m[rb] = mn;
        f32x4 alv;
#pragma unroll
        for (int r = 0; r < 4; ++r)
          alv[r] = __shfl(alpha, lg * 4 + r, 64);    // alpha of q-row lg*4+r
        accl[rb] *= alv;
#pragma unroll
        for (int ct = 0; ct < 8; ++ct) acc[rb][ct] *= alv;
      }
      f16x8 pp;
      pp[0] = (_Float16)fast_exp2(s[0][rb][0] - m[rb]);
      pp[1] = (_Float16)fast_exp2(s[0][rb][1] - m[rb]);
      pp[2] = (_Float16)fast_exp2(s[0][rb][2] - m[rb]);
      pp[3] = (_Float16)fast_exp2(s[0][rb][3] - m[rb]);
      pp[4] = (_Float16)fast_exp2(s[1][rb][0] - m[rb]);
      pp[5] = (_Float16)fast_exp2(s[1][rb][1] - m[rb]);
      pp[6] = (_Float16)fast_exp2(s[1][rb][2] - m[rb]);
      pp[7] = (_Float16)fast_exp2(s[1][rb][3] - m[rb]);
      pa[rb] = pp;                                   // k-slot j = kv 8*lg+j
    }

    // ---- PV + indicator row-sum on resident vbuf[p] (issued a tile ago) ----
    __builtin_amdgcn_s_setprio(1);
#pragma unroll
    for (int ct = 0; ct < 8; ++ct) {
      acc[0][ct] = __builtin_amdgcn_mfma_f32_16x16x32_f16(pa[0], vbuf[p][ct], acc[0][ct], 0, 0, 0);
      acc[1][ct] = __builtin_amdgcn_mfma_f32_16x16x32_f16(pa[1], vbuf[p][ct], acc[1][ct], 0, 0, 0);
    }
    accl[0] = __builtin_amdgcn_mfma_f32_16x16x32_f16(pa[0], indf, accl[0], 0, 0, 0);
    accl[1] = __builtin_amdgcn_mfma_f32_16x16x32_f16(pa[1], indf, accl[1], 0, 0, 0);
    __builtin_amdgcn_s_setprio(0);
  }

  // ---- publish per-wave stats ----
  if (lg == 0) {                           // lanes 0-15: m for q-row l15
    msh[w][l15]      = m[0];
    msh[w][16 + l15] = m[1];
  }
  if (l15 == 0) {
#pragma unroll
    for (int rb = 0; rb < 2; ++rb)
#pragma unroll
      for (int r = 0; r < 4; ++r)
        lsh[w][rb * 16 + lg * 4 + r] = accl[rb][r];
  }
  __syncthreads();

  // per-wave rescale coefficient to the block max (acc layout: q = lg*4+r)
  float coef[2][4];
#pragma unroll
  for (int rb = 0; rb < 2; ++rb)
#pragma unroll
    for (int r = 0; r < 4; ++r) {
      int row = rb * 16 + lg * 4 + r;
      float mstar = msh[0][row];
#pragma unroll
      for (int wv = 1; wv < NWV; ++wv) mstar = fmaxf(mstar, msh[wv][row]);
      coef[rb][r] = fast_exp2(msh[w][row] - mstar);
    }

  // sequential accumulate into osh (NWV barriers, epilogue-only)
#pragma unroll
  for (int wv = 0; wv < NWV; ++wv) {
    if (w == wv) {
#pragma unroll
      for (int rb = 0; rb < 2; ++rb)
#pragma unroll
        for (int ct = 0; ct < 8; ++ct)
#pragma unroll
          for (int r = 0; r < 4; ++r) {
            int idx = (rb * 16 + lg * 4 + r) * 132 + ct * 16 + l15;
            float val = coef[rb][r] * acc[rb][ct][r];
            if (wv == 0) osh[idx] = val; else osh[idx] += val;
          }
    }
    __syncthreads();
  }

  // ---- final normalize + query-mask + store ----
  {
    const int row = tid >> 3;            // 0..31
    const int cg = (tid & 7) * 16;       // 0..112
    float mstar = msh[0][row];
#pragma unroll
    for (int wv = 1; wv < NWV; ++wv) mstar = fmaxf(mstar, msh[wv][row]);
    float lstar = 0.f;
#pragma unroll
    for (int wv = 0; wv < NWV; ++wv)
      lstar += fast_exp2(msh[wv][row] - mstar) * lsh[wv][row];
    const int qr = qbase + row;
    const float f = ((mask_q[(size_t)b * TQ + qr] != 0) ? 1.f : 0.f) / lstar;
    float* orow = out + ((size_t)b * TQ + qr) * DD + cg;
#pragma unroll
    for (int i4 = 0; i4 < 4; ++i4) {
      float4 p = *(float4*)&osh[row * 132 + cg + i4 * 4];
      float4 o; o.x = p.x * f; o.y = p.y * f; o.z = p.z * f; o.w = p.w * f;
      *(float4*)(orow + i4 * 4) = o;
    }
  }
}

// ---------------- fallback (round-1 kernel) if ws too small --------------------
__global__ __launch_bounds__(64, 4) void attn_f32_kernel(
    const float* __restrict__ q, const float* __restrict__ v,
    const float* __restrict__ k, const float* __restrict__ scale_p,
    const int* __restrict__ mask_q, const int* __restrict__ mask_v,
    float* __restrict__ out)
{
  __shared__ __align__(16) _Float16 plds[16 * 40];
  const int lane = threadIdx.x & 63;
  const int l15 = lane & 15, lg = lane >> 4;
  const int qblocks = TQ / 16;
  const int b = blockIdx.x / qblocks, qb = blockIdx.x % qblocks;
  const int qbase = qb * 16;
  const float scale = scale_p[0];
  const float* qp = q + ((size_t)b * TQ + qbase) * DD;
  const float* kbase = k + (size_t)b * TV * DD;
  const float* vbase = v + (size_t)b * TV * DD;
  const int* mvb = mask_v + b * TV;
  f16x8 qf[4];
#pragma unroll
  for (int kc = 0; kc < 4; ++kc) {
    float4 a = *(const float4*)(qp + (size_t)l15 * DD + kc * 32 + lg * 8);
    float4 bb = *(const float4*)(qp + (size_t)l15 * DD + kc * 32 + lg * 8 + 4);
    f16x8 h; h[0]=(_Float16)a.x;h[1]=(_Float16)a.y;h[2]=(_Float16)a.z;h[3]=(_Float16)a.w;
    h[4]=(_Float16)bb.x;h[5]=(_Float16)bb.y;h[6]=(_Float16)bb.z;h[7]=(_Float16)bb.w;
    qf[kc]=h;
  }
  f32x4 acc[8];
#pragma unroll
  for (int i = 0; i < 8; ++i) acc[i] = (f32x4){0.f,0.f,0.f,0.f};
  float m[4], lsum[4];
#pragma unroll
  for (int r = 0; r < 4; ++r) { m[r] = -3.0e38f; lsum[r] = 0.f; }
  for (int kt = 0; kt < TV; kt += KVT) {
    f32x4 s0 = {0,0,0,0}, s1 = {0,0,0,0};
#pragma unroll
    for (int kc = 0; kc < 4; ++kc) {
      const float* kp0 = kbase + (size_t)(kt + l15) * DD + kc * 32 + lg * 8;
      float4 a = *(const float4*)kp0; float4 bb = *(const float4*)(kp0 + 4);
      f16x8 kf0; kf0[0]=(_Float16)a.x;kf0[1]=(_Float16)a.y;kf0[2]=(_Float16)a.z;kf0[3]=(_Float16)a.w;
      kf0[4]=(_Float16)bb.x;kf0[5]=(_Float16)bb.y;kf0[6]=(_Float16)bb.z;kf0[7]=(_Float16)bb.w;
      s0 = __builtin_amdgcn_mfma_f32_16x16x32_f16(qf[kc], kf0, s0, 0, 0, 0);
      const float* kp1 = kbase + (size_t)(kt + 16 + l15) * DD + kc * 32 + lg * 8;
      a = *(const float4*)kp1; bb = *(const float4*)(kp1 + 4);
      f16x8 kf1; kf1[0]=(_Float16)a.x;kf1[1]=(_Float16)a.y;kf1[2]=(_Float16)a.z;kf1[3]=(_Float16)a.w;
      kf1[4]=(_Float16)bb.x;kf1[5]=(_Float16)bb.y;kf1[6]=(_Float16)bb.z;kf1[7]=(_Float16)bb.w;
      s1 = __builtin_amdgcn_mfma_f32_16x16x32_f16(qf[kc], kf1, s1, 0, 0, 0);
    }
    const float a0 = (mvb[kt + l15] != 0) ? 0.f : -1e9f;
    const float a1 = (mvb[kt + 16 + l15] != 0) ? 0.f : -1e9f;
    float pmx[4];
#pragma unroll
    for (int r = 0; r < 4; ++r) {
      s0[r] = s0[r] * scale + a0; s1[r] = s1[r] * scale + a1;
      pmx[r] = fmaxf(s0[r], s1[r]);
    }
#pragma unroll
    for (int off = 1; off < 16; off <<= 1)
#pragma unroll
      for (int r = 0; r < 4; ++r) pmx[r] = fmaxf(pmx[r], __shfl_xor(pmx[r], off, 64));
    float al[4], ps[4];
#pragma unroll
    for (int r = 0; r < 4; ++r) {
      float mn = fmaxf(m[r], pmx[r]);
      al[r] = __expf(m[r] - mn); m[r] = mn;
      float p0 = __expf(s0[r] - mn), p1 = __expf(s1[r] - mn);
      ps[r] = p0 + p1;
      int row = lg * 4 + r;
      plds[row * 40 + l15] = (_Float16)p0;
      plds[row * 40 + 16 + l15] = (_Float16)p1;
    }
#pragma unroll
    for (int off = 1; off < 16; off <<= 1)
#pragma unroll
      for (int r = 0; r < 4; ++r) ps[r] += __shfl_xor(ps[r], off, 64);
#pragma unroll
    for (int r = 0; r < 4; ++r) {
      lsum[r] = lsum[r] * al[r] + ps[r];
#pragma unroll
      for (int ct = 0; ct < 8; ++ct) acc[ct][r] *= al[r];
    }
    f16x8 pa = *(const f16x8*)&plds[l15 * 40 + lg * 8];
#pragma unroll
    for (int ct = 0; ct < 8; ++ct) {
      const float* vp = vbase + (size_t)(kt + lg * 8) * DD + ct * 16 + l15;
      f16x8 vfx;
#pragma unroll
      for (int j = 0; j < 8; ++j) vfx[j] = (_Float16)vp[(size_t)j * DD];
      acc[ct] = __builtin_amdgcn_mfma_f32_16x16x32_f16(pa, vfx, acc[ct], 0, 0, 0);
    }
  }
  const int* mqb = mask_q + b * TQ;
#pragma unroll
  for (int r = 0; r < 4; ++r) {
    int row = lg * 4 + r;
    int qr = qbase + row;
    float f = ((mqb[qr] != 0) ? 1.f : 0.f) / lsum[r];
    float* orow = out + ((size_t)b * TQ + qr) * DD;
#pragma unroll
    for (int ct = 0; ct < 8; ++ct) orow[ct * 16 + l15] = acc[ct][r] * f;
  }
}

extern "C" void kernel_launch(void* const* d_in, const int* in_sizes, int n_in,
                              void* d_out, int out_size, void* d_ws, size_t ws_size,
                              hipStream_t stream) {
  const float* q      = (const float*)d_in[0];
  const float* v      = (const float*)d_in[1];
  const float* k      = (const float*)d_in[2];
  const float* scale  = (const float*)d_in[3];
  const int*   mask_q = (const int*)d_in[4];
  const int*   mask_v = (const int*)d_in[5];
  float* out = (float*)d_out;

  const size_t kvBytes = 2ull * NB * TV * DD * sizeof(_Float16);  // 8 MB
  const size_t indBytes = (size_t)NB * TV * sizeof(_Float16);     // 32 KB
  if (ws_size >= kvBytes + indBytes) {
    _Float16* kh2 = (_Float16*)d_ws;
    _Float16* vt2 = kh2 + (size_t)NB * TV * DD;
    _Float16* indb = vt2 + (size_t)NB * TV * DD;
    hipLaunchKernelGGL(prepass_kernel, dim3(512 + 2048 + 16), dim3(256), 0, stream,
                       k, v, mask_v, kh2, vt2, indb);
    hipLaunchKernelGGL(attn_main, dim3(NB * (TQ / 32)), dim3(256), 0, stream,
                       q, scale, kh2, vt2, indb, mask_q, out);
  } else {
    hipLaunchKernelGGL(attn_f32_kernel, dim3(NB * (TQ / 16)), dim3(64), 0, stream,
                       q, v, k, scale, mask_q, mask_v, out);
  }
}

// Round 18
// 53.304 us; speedup vs baseline: 1.0201x; 1.0201x over previous
//
#include <hip/hip_runtime.h>
#include <cstddef>

#define NB 8
#define TQ 2048
#define TV 2048
#define DD 128
#define KVT 32
#define NWV 4           // waves per block; chunk = 512 KV rows/wave (PROVEN shape)
#define CHW (TV / NWV)  // 512
#define NT  (CHW / KVT) // 16 tiles per wave
#define LOG2E 1.4426950408889634f

typedef _Float16 f16x8 __attribute__((ext_vector_type(8)));
typedef _Float16 f16x4 __attribute__((ext_vector_type(4)));
typedef float f32x4 __attribute__((ext_vector_type(4)));

__device__ __forceinline__ float fast_exp2(float x) {
  return __builtin_amdgcn_exp2f(x);      // v_exp_f32 (computes 2^x)
}

// ------- prepass (r15-verified, unchanged) ----------------------------------
__global__ __launch_bounds__(256) void prepass_kernel(
    const float* __restrict__ k, const float* __restrict__ v,
    const int* __restrict__ mask_v,
    _Float16* __restrict__ kh2, _Float16* __restrict__ vt2,
    _Float16* __restrict__ indb)
{
  __shared__ _Float16 tlds[32 * 34];
  const int tid = threadIdx.x;
  const int bid = blockIdx.x;
  if (bid < 512) {                        // K tiles: one 32x128 tile per block
    int b = bid >> 6, kt = bid & 63;
    int row = tid >> 3, d0 = (tid & 7) * 4;          // row = original kv 0..31
    int R = 16 * ((row >> 2) & 1) + 4 * (row >> 3) + (row & 3);  // storage row
    const float* src = k + ((size_t)(b * TV + kt * 32 + row)) * DD;
    _Float16* dst = kh2 + ((size_t)(b * 64 + kt)) * 4096;
#pragma unroll
    for (int it = 0; it < 4; ++it) {      // kc = it
      float4 x = *(const float4*)(src + it * 32 + d0);
      f16x4 h; h[0] = (_Float16)x.x; h[1] = (_Float16)x.y;
      h[2] = (_Float16)x.z; h[3] = (_Float16)x.w;
      *(f16x4*)(dst + it * 1024 + R * 32 + d0) = h;
    }
  } else if (bid < 512 + 2048) {          // V transpose tiles 32x32 (masked->0)
    int tb = bid - 512;                   // 8 b * 64 kt * 4 dt
    int b = tb >> 8, rem = tb & 255;
    int kt = rem >> 2, dt = rem & 3;
    int r = tid >> 3, c0 = (tid & 7) * 4;
    float mfac = (mask_v[(size_t)b * TV + kt * 32 + r] != 0) ? 1.f : 0.f;
    float4 x = *(const float4*)&v[((size_t)b * TV + kt * 32 + r) * DD + dt * 32 + c0];
    tlds[(c0 + 0) * 34 + r] = (_Float16)(mfac * x.x);
    tlds[(c0 + 1) * 34 + r] = (_Float16)(mfac * x.y);
    tlds[(c0 + 2) * 34 + r] = (_Float16)(mfac * x.z);
    tlds[(c0 + 3) * 34 + r] = (_Float16)(mfac * x.w);
    __syncthreads();
    int dl = tid >> 3, k0 = (tid & 7) * 4;
    f16x4 h;
#pragma unroll
    for (int i = 0; i < 4; ++i) h[i] = tlds[dl * 34 + k0 + i];
    size_t eidx = (((size_t)b * 64 + kt) * 128 + (dt * 32 + dl)) * 32 + k0;
    *(f16x4*)&vt2[eidx] = h;
  } else {                                // indicator build: 16 blocks
    int bid2 = bid - 512 - 2048;
    size_t base = (size_t)bid2 * 1024 + tid * 4;
#pragma unroll
    for (int i = 0; i < 4; ++i)
      indb[base + i] = (mask_v[base + i] != 0) ? (_Float16)1.f : (_Float16)0.f;
  }
}

// ------- main: rotated 2-tile score pipeline (QK(t+1) before softmax(t)) ------
__global__ __launch_bounds__(256, 2) void attn_main(
    const float* __restrict__ q, const float* __restrict__ scale_p,
    const _Float16* __restrict__ kh2, const _Float16* __restrict__ vt2,
    const _Float16* __restrict__ indb,
    const int* __restrict__ mask_q, float* __restrict__ out)
{
  __shared__ __align__(16) float osh[32 * 132];
  __shared__ float msh[NWV][32], lsh[NWV][32];

  const int tid = threadIdx.x;
  const int w = tid >> 6;
  const int lane = tid & 63;
  const int l15 = lane & 15, lg = lane >> 4;

  const int b = blockIdx.x & 7;            // batch -> XCD affinity (proven mapping)
  const int qg = blockIdx.x >> 3;          // 0..63
  const int qbase = qg * 32;

  const _Float16* ktiles = kh2 + (size_t)b * 64 * 4096;
  const _Float16* vtiles = vt2 + (size_t)b * 64 * 4096;
  const _Float16* indbt = indb + (size_t)b * TV;

  const float sc2 = scale_p[0] * LOG2E;
  f16x8 qf[2][4];
#pragma unroll
  for (int rb = 0; rb < 2; ++rb)
#pragma unroll
    for (int kc = 0; kc < 4; ++kc) {
      const float* qp = q + ((size_t)b * TQ + qbase + rb * 16 + l15) * DD + kc * 32 + lg * 8;
      float4 xa = *(const float4*)qp;
      float4 xb = *(const float4*)(qp + 4);
      f16x8 h;
      h[0] = (_Float16)(sc2 * xa.x); h[1] = (_Float16)(sc2 * xa.y);
      h[2] = (_Float16)(sc2 * xa.z); h[3] = (_Float16)(sc2 * xa.w);
      h[4] = (_Float16)(sc2 * xb.x); h[5] = (_Float16)(sc2 * xb.y);
      h[6] = (_Float16)(sc2 * xb.z); h[7] = (_Float16)(sc2 * xb.w);
      qf[rb][kc] = h;
    }

  f32x4 acc[2][8];
  f32x4 accl[2];
#pragma unroll
  for (int rb = 0; rb < 2; ++rb) {
    accl[rb] = (f32x4){0.f, 0.f, 0.f, 0.f};
#pragma unroll
    for (int ct = 0; ct < 8; ++ct) acc[rb][ct] = (f32x4){0.f, 0.f, 0.f, 0.f};
  }
  float m[2];
  m[0] = -3.0e38f; m[1] = -3.0e38f;

  const int tbase = w * NT;

  f16x8 kbuf[8], vbuf[8];
  f16x8 ib0, ib1;

  auto load_k = [&](int tile) {
    const _Float16* ktb = ktiles + (size_t)tile * 4096;
#pragma unroll
    for (int kc = 0; kc < 4; ++kc) {
      kbuf[2 * kc]     = *(const f16x8*)(ktb + kc * 1024 + l15 * 32 + lg * 8);
      kbuf[2 * kc + 1] = *(const f16x8*)(ktb + kc * 1024 + (16 + l15) * 32 + lg * 8);
    }
  };
  auto load_v = [&](int tile) {
    const _Float16* vtb = vtiles + (size_t)tile * 4096;
#pragma unroll
    for (int ct = 0; ct < 8; ++ct)
      vbuf[ct] = *(const f16x8*)(vtb + (ct * 16 + l15) * 32 + lg * 8);
  };
  auto do_qk = [&](f32x4 (&s)[2][2]) {
    s[0][0] = (f32x4){0,0,0,0}; s[0][1] = (f32x4){0,0,0,0};
    s[1][0] = (f32x4){0,0,0,0}; s[1][1] = (f32x4){0,0,0,0};
    __builtin_amdgcn_s_setprio(1);
#pragma unroll
    for (int kc = 0; kc < 4; ++kc) {
      s[0][0] = __builtin_amdgcn_mfma_f32_16x16x32_f16(kbuf[2*kc],   qf[0][kc], s[0][0], 0, 0, 0);
      s[0][1] = __builtin_amdgcn_mfma_f32_16x16x32_f16(kbuf[2*kc],   qf[1][kc], s[0][1], 0, 0, 0);
      s[1][0] = __builtin_amdgcn_mfma_f32_16x16x32_f16(kbuf[2*kc+1], qf[0][kc], s[1][0], 0, 0, 0);
      s[1][1] = __builtin_amdgcn_mfma_f32_16x16x32_f16(kbuf[2*kc+1], qf[1][kc], s[1][1], 0, 0, 0);
    }
    __builtin_amdgcn_s_setprio(0);
  };
  // softmax(cur) + PV(cur): uses resident vbuf=V(cur) and indf=ind(cur)
  auto do_sm_pv = [&](f32x4 (&s)[2][2], const f16x8& indf) {
    f16x8 pa[2];
#pragma unroll
    for (int rb = 0; rb < 2; ++rb) {
#pragma unroll
      for (int r = 0; r < 4; ++r) {
        s[0][rb][r] += ((float)indf[r]     - 1.f) * 60000.f;
        s[1][rb][r] += ((float)indf[4 + r] - 1.f) * 60000.f;
      }
      float lm = fmaxf(fmaxf(fmaxf(s[0][rb][0], s[0][rb][1]), fmaxf(s[0][rb][2], s[0][rb][3])),
                       fmaxf(fmaxf(s[1][rb][0], s[1][rb][1]), fmaxf(s[1][rb][2], s[1][rb][3])));
      if (__any(lm > m[rb] + 11.5f)) {      // rare: full rowmax + rescale
        float pm = lm;
        pm = fmaxf(pm, __shfl_xor(pm, 16, 64));
        pm = fmaxf(pm, __shfl_xor(pm, 32, 64));
        float mn = fmaxf(m[rb], pm);
        float alpha = fast_exp2(m[rb] - mn);
        m[rb] = mn;
        f32x4 alv;
#pragma unroll
        for (int r = 0; r < 4; ++r)
          alv[r] = __shfl(alpha, lg * 4 + r, 64);
        accl[rb] *= alv;
#pragma unroll
        for (int ct = 0; ct < 8; ++ct) acc[rb][ct] *= alv;
      }
      f16x8 pp;
      pp[0] = (_Float16)fast_exp2(s[0][rb][0] - m[rb]);
      pp[1] = (_Float16)fast_exp2(s[0][rb][1] - m[rb]);
      pp[2] = (_Float16)fast_exp2(s[0][rb][2] - m[rb]);
      pp[3] = (_Float16)fast_exp2(s[0][rb][3] - m[rb]);
      pp[4] = (_Float16)fast_exp2(s[1][rb][0] - m[rb]);
      pp[5] = (_Float16)fast_exp2(s[1][rb][1] - m[rb]);
      pp[6] = (_Float16)fast_exp2(s[1][rb][2] - m[rb]);
      pp[7] = (_Float16)fast_exp2(s[1][rb][3] - m[rb]);
      pa[rb] = pp;
    }
    __builtin_amdgcn_s_setprio(1);
#pragma unroll
    for (int ct = 0; ct < 8; ++ct) {
      acc[0][ct] = __builtin_amdgcn_mfma_f32_16x16x32_f16(pa[0], vbuf[ct], acc[0][ct], 0, 0, 0);
      acc[1][ct] = __builtin_amdgcn_mfma_f32_16x16x32_f16(pa[1], vbuf[ct], acc[1][ct], 0, 0, 0);
    }
    accl[0] = __builtin_amdgcn_mfma_f32_16x16x32_f16(pa[0], indf, accl[0], 0, 0, 0);
    accl[1] = __builtin_amdgcn_mfma_f32_16x16x32_f16(pa[1], indf, accl[1], 0, 0, 0);
    __builtin_amdgcn_s_setprio(0);
  };

  f32x4 sA[2][2], sB[2][2];

  // ---- prologue: K(0) -> QK(0) -> sA; refill K(1); ind(0),ind(1); V(0) ----
  load_k(tbase);
  ib0 = *(const f16x8*)(indbt + tbase * 32 + lg * 8);
  do_qk(sA);                                // tile 0 scores
  load_k(tbase + 1);                        // post-use refill
  ib1 = *(const f16x8*)(indbt + (tbase + 1) * 32 + lg * 8);
  load_v(tbase);

#pragma unroll
  for (int tp = 0; tp < NT / 2; ++tp) {
    const int t0 = 2 * tp;
    // ---- even phase: cur = tile t0 (sA), compute QK(t0+1) first ----
    do_qk(sB);                              // consumes kbuf = K(t0+1)
    if (t0 + 2 < NT) load_k(tbase + t0 + 2);  // post-use refill
    do_sm_pv(sA, ib0);                      // softmax+PV tile t0 (vbuf=V(t0))
    load_v(tbase + t0 + 1);                 // post-use refill (t0+1 < NT always)
    if (t0 + 2 < NT) ib0 = *(const f16x8*)(indbt + (tbase + t0 + 2) * 32 + lg * 8);
    // ---- odd phase: cur = tile t0+1 (sB), compute QK(t0+2) first ----
    if (t0 + 2 < NT) {
      do_qk(sA);                            // consumes kbuf = K(t0+2)
      if (t0 + 3 < NT) load_k(tbase + t0 + 3);
    }
    do_sm_pv(sB, ib1);                      // softmax+PV tile t0+1 (vbuf=V(t0+1))
    if (t0 + 2 < NT) {
      load_v(tbase + t0 + 2);
      if (t0 + 3 < NT) ib1 = *(const f16x8*)(indbt + (tbase + t0 + 3) * 32 + lg * 8);
    }
  }

  // ---- publish per-wave stats ----
  if (lg == 0) {
    msh[w][l15]      = m[0];
    msh[w][16 + l15] = m[1];
  }
  if (l15 == 0) {
#pragma unroll
    for (int rb = 0; rb < 2; ++rb)
#pragma unroll
      for (int r = 0; r < 4; ++r)
        lsh[w][rb * 16 + lg * 4 + r] = accl[rb][r];
  }
  __syncthreads();

  float coef[2][4];
#pragma unroll
  for (int rb = 0; rb < 2; ++rb)
#pragma unroll
    for (int r = 0; r < 4; ++r) {
      int row = rb * 16 + lg * 4 + r;
      float mstar = msh[0][row];
#pragma unroll
      for (int wv = 1; wv < NWV; ++wv) mstar = fmaxf(mstar, msh[wv][row]);
      coef[rb][r] = fast_exp2(msh[w][row] - mstar);
    }

#pragma unroll
  for (int wv = 0; wv < NWV; ++wv) {
    if (w == wv) {
#pragma unroll
      for (int rb = 0; rb < 2; ++rb)
#pragma unroll
        for (int ct = 0; ct < 8; ++ct)
#pragma unroll
          for (int r = 0; r < 4; ++r) {
            int idx = (rb * 16 + lg * 4 + r) * 132 + ct * 16 + l15;
            float val = coef[rb][r] * acc[rb][ct][r];
            if (wv == 0) osh[idx] = val; else osh[idx] += val;
          }
    }
    __syncthreads();
  }

  {
    const int row = tid >> 3;
    const int cg = (tid & 7) * 16;
    float mstar = msh[0][row];
#pragma unroll
    for (int wv = 1; wv < NWV; ++wv) mstar = fmaxf(mstar, msh[wv][row]);
    float lstar = 0.f;
#pragma unroll
    for (int wv = 0; wv < NWV; ++wv)
      lstar += fast_exp2(msh[wv][row] - mstar) * lsh[wv][row];
    const int qr = qbase + row;
    const float f = ((mask_q[(size_t)b * TQ + qr] != 0) ? 1.f : 0.f) / lstar;
    float* orow = out + ((size_t)b * TQ + qr) * DD + cg;
#pragma unroll
    for (int i4 = 0; i4 < 4; ++i4) {
      float4 p = *(float4*)&osh[row * 132 + cg + i4 * 4];
      float4 o; o.x = p.x * f; o.y = p.y * f; o.z = p.z * f; o.w = p.w * f;
      *(float4*)(orow + i4 * 4) = o;
    }
  }
}

// ---------------- fallback (round-1 kernel) if ws too small --------------------
__global__ __launch_bounds__(64, 4) void attn_f32_kernel(
    const float* __restrict__ q, const float* __restrict__ v,
    const float* __restrict__ k, const float* __restrict__ scale_p,
    const int* __restrict__ mask_q, const int* __restrict__ mask_v,
    float* __restrict__ out)
{
  __shared__ __align__(16) _Float16 plds[16 * 40];
  const int lane = threadIdx.x & 63;
  const int l15 = lane & 15, lg = lane >> 4;
  const int qblocks = TQ / 16;
  const int b = blockIdx.x / qblocks, qb = blockIdx.x % qblocks;
  const int qbase = qb * 16;
  const float scale = scale_p[0];
  const float* qp = q + ((size_t)b * TQ + qbase) * DD;
  const float* kbase = k + (size_t)b * TV * DD;
  const float* vbase = v + (size_t)b * TV * DD;
  const int* mvb = mask_v + b * TV;
  f16x8 qf[4];
#pragma unroll
  for (int kc = 0; kc < 4; ++kc) {
    float4 a = *(const float4*)(qp + (size_t)l15 * DD + kc * 32 + lg * 8);
    float4 bb = *(const float4*)(qp + (size_t)l15 * DD + kc * 32 + lg * 8 + 4);
    f16x8 h; h[0]=(_Float16)a.x;h[1]=(_Float16)a.y;h[2]=(_Float16)a.z;h[3]=(_Float16)a.w;
    h[4]=(_Float16)bb.x;h[5]=(_Float16)bb.y;h[6]=(_Float16)bb.z;h[7]=(_Float16)bb.w;
    qf[kc]=h;
  }
  f32x4 acc[8];
#pragma unroll
  for (int i = 0; i < 8; ++i) acc[i] = (f32x4){0.f,0.f,0.f,0.f};
  float m[4], lsum[4];
#pragma unroll
  for (int r = 0; r < 4; ++r) { m[r] = -3.0e38f; lsum[r] = 0.f; }
  for (int kt = 0; kt < TV; kt += KVT) {
    f32x4 s0 = {0,0,0,0}, s1 = {0,0,0,0};
#pragma unroll
    for (int kc = 0; kc < 4; ++kc) {
      const float* kp0 = kbase + (size_t)(kt + l15) * DD + kc * 32 + lg * 8;
      float4 a = *(const float4*)kp0; float4 bb = *(const float4*)(kp0 + 4);
      f16x8 kf0; kf0[0]=(_Float16)a.x;kf0[1]=(_Float16)a.y;kf0[2]=(_Float16)a.z;kf0[3]=(_Float16)a.w;
      kf0[4]=(_Float16)bb.x;kf0[5]=(_Float16)bb.y;kf0[6]=(_Float16)bb.z;kf0[7]=(_Float16)bb.w;
      s0 = __builtin_amdgcn_mfma_f32_16x16x32_f16(qf[kc], kf0, s0, 0, 0, 0);
      const float* kp1 = kbase + (size_t)(kt + 16 + l15) * DD + kc * 32 + lg * 8;
      a = *(const float4*)kp1; bb = *(const float4*)(kp1 + 4);
      f16x8 kf1; kf1[0]=(_Float16)a.x;kf1[1]=(_Float16)a.y;kf1[2]=(_Float16)a.z;kf1[3]=(_Float16)a.w;
      kf1[4]=(_Float16)bb.x;kf1[5]=(_Float16)bb.y;kf1[6]=(_Float16)bb.z;kf1[7]=(_Float16)bb.w;
      s1 = __builtin_amdgcn_mfma_f32_16x16x32_f16(qf[kc], kf1, s1, 0, 0, 0);
    }
    const float a0 = (mvb[kt + l15] != 0) ? 0.f : -1e9f;
    const float a1 = (mvb[kt + 16 + l15] != 0) ? 0.f : -1e9f;
    float pmx[4];
#pragma unroll
    for (int r = 0; r < 4; ++r) {
      s0[r] = s0[r] * scale + a0; s1[r] = s1[r] * scale + a1;
      pmx[r] = fmaxf(s0[r], s1[r]);
    }
#pragma unroll
    for (int off = 1; off < 16; off <<= 1)
#pragma unroll
      for (int r = 0; r < 4; ++r) pmx[r] = fmaxf(pmx[r], __shfl_xor(pmx[r], off, 64));
    float al[4], ps[4];
#pragma unroll
    for (int r = 0; r < 4; ++r) {
      float mn = fmaxf(m[r], pmx[r]);
      al[r] = __expf(m[r] - mn); m[r] = mn;
      float p0 = __expf(s0[r] - mn), p1 = __expf(s1[r] - mn);
      ps[r] = p0 + p1;
      int row = lg * 4 + r;
      plds[row * 40 + l15] = (_Float16)p0;
      plds[row * 40 + 16 + l15] = (_Float16)p1;
    }
#pragma unroll
    for (int off = 1; off < 16; off <<= 1)
#pragma unroll
      for (int r = 0; r < 4; ++r) ps[r] += __shfl_xor(ps[r], off, 64);
#pragma unroll
    for (int r = 0; r < 4; ++r) {
      lsum[r] = lsum[r] * al[r] + ps[r];
#pragma unroll
      for (int ct = 0; ct < 8; ++ct) acc[ct][r] *= al[r];
    }
    f16x8 pa = *(const f16x8*)&plds[l15 * 40 + lg * 8];
#pragma unroll
    for (int ct = 0; ct < 8; ++ct) {
      const float* vp = vbase + (size_t)(kt + lg * 8) * DD + ct * 16 + l15;
      f16x8 vfx;
#pragma unroll
      for (int j = 0; j < 8; ++j) vfx[j] = (_Float16)vp[(size_t)j * DD];
      acc[ct] = __builtin_amdgcn_mfma_f32_16x16x32_f16(pa, vfx, acc[ct], 0, 0, 0);
    }
  }
  const int* mqb = mask_q + b * TQ;
#pragma unroll
  for (int r = 0; r < 4; ++r) {
    int row = lg * 4 + r;
    int qr = qbase + row;
    float f = ((mqb[qr] != 0) ? 1.f : 0.f) / lsum[r];
    float* orow = out + ((size_t)b * TQ + qr) * DD;
#pragma unroll
    for (int ct = 0; ct < 8; ++ct) orow[ct * 16 + l15] = acc[ct][r] * f;
  }
}

extern "C" void kernel_launch(void* const* d_in, const int* in_sizes, int n_in,
                              void* d_out, int out_size, void* d_ws, size_t ws_size,
                              hipStream_t stream) {
  const float* q      = (const float*)d_in[0];
  const float* v      = (const float*)d_in[1];
  const float* k      = (const float*)d_in[2];
  const float* scale  = (const float*)d_in[3];
  const int*   mask_q = (const int*)d_in[4];
  const int*   mask_v = (const int*)d_in[5];
  float* out = (float*)d_out;

  const size_t kvBytes = 2ull * NB * TV * DD * sizeof(_Float16);  // 8 MB
  const size_t indBytes = (size_t)NB * TV * sizeof(_Float16);     // 32 KB
  if (ws_size >= kvBytes + indBytes) {
    _Float16* kh2 = (_Float16*)d_ws;
    _Float16* vt2 = kh2 + (size_t)NB * TV * DD;
    _Float16* indb = vt2 + (size_t)NB * TV * DD;
    hipLaunchKernelGGL(prepass_kernel, dim3(512 + 2048 + 16), dim3(256), 0, stream,
                       k, v, mask_v, kh2, vt2, indb);
    hipLaunchKernelGGL(attn_main, dim3(NB * (TQ / 32)), dim3(256), 0, stream,
                       q, scale, kh2, vt2, indb, mask_q, out);
  } else {
    hipLaunchKernelGGL(attn_f32_kernel, dim3(NB * (TQ / 16)), dim3(64), 0, stream,
                       q, v, k, scale, mask_q, mask_v, out);
  }
}